// Round 2
// baseline (781.919 us; speedup 1.0000x reference)
//
#include <hip/hip_runtime.h>

#define N_NODES 50000
#define N_EDGES 600000
#define DIM 128
#define NBLK_MLP ((N_NODES + 127) / 128)   // 391

typedef __attribute__((ext_vector_type(8))) short s16x8;
typedef __attribute__((ext_vector_type(8))) unsigned short u16x8;
typedef __attribute__((ext_vector_type(4))) float f32x4;
typedef __attribute__((ext_vector_type(2))) float f32x2;

__device__ __forceinline__ unsigned short f2b(float f) {
    union { float f; unsigned int i; } v;
    v.f = f;
    unsigned int i = v.i;
    return (unsigned short)((i + 0x7FFFu + ((i >> 16) & 1u)) >> 16);
}

// pack 8 fp32 -> 8 bf16 (RNE)
__device__ __forceinline__ s16x8 cvt8(f32x4 a, f32x4 b) {
    union { u16x8 u; s16x8 s; } t;
#pragma unroll
    for (int j = 0; j < 4; j++) { t.u[j] = f2b(a[j]); t.u[4 + j] = f2b(b[j]); }
    return t.s;
}

// ---------------------------------------------------------------------------
// Phase A: payload sort. Edges are processed in NATURAL order (ea streams
// sequentially); the computed message relu(x[src]+ea) is written fp32 into
// its CSR slot (random 512B write, L2/L3-buffered). The segment-sum then
// reads messages FULLY SEQUENTIALLY. This removes the 600+ MB random-read
// stream that bound the old k_gather (round-1 A/B: 4x ILP changed nothing ->
// throughput-bound on random granules, not latency).
//
// d_out scratch (dead until k_mlp writes h2):
//   off     int[50001]   @ byte 0
//   cursor  int[50000]   @ byte 200,064   (= count during k_hist)
// ws: agg fp32[50000][128] @ 0;  msg fp32[600000][128] @ 32 MiB (293 MB;
//     harness poison fill shows ws >= 1.2 GB)
// ---------------------------------------------------------------------------

// K0a: histogram of destinations
__global__ __launch_bounds__(256) void k_hist(
    const int* __restrict__ ei, int* __restrict__ count)
{
    int t = blockIdx.x * 256 + threadIdx.x;
    if (t < N_EDGES) atomicAdd(&count[ei[N_EDGES + t]], 1);
}

// K0b: exclusive scan of counts -> off[0..N]; cursor[v] = off[v] (in place)
__global__ __launch_bounds__(1024) void k_scan(
    int* __restrict__ off, int* cnt_cur)
{
    __shared__ int part[1024];
    const int CH = (N_NODES + 1023) / 1024;  // 49
    const int t = threadIdx.x;
    const int lo = t * CH;
    const int hi = (lo + CH < N_NODES) ? lo + CH : N_NODES;
    int s = 0;
    for (int v = lo; v < hi; v++) s += cnt_cur[v];
    part[t] = s;
    __syncthreads();
    for (int d = 1; d < 1024; d <<= 1) {
        int val = (t >= d) ? part[t - d] : 0;
        __syncthreads();
        part[t] += val;
        __syncthreads();
    }
    int run = (t == 0) ? 0 : part[t - 1];
    for (int v = lo; v < hi; v++) {
        int c = cnt_cur[v];
        off[v] = run;
        cnt_cur[v] = run;
        run += c;
    }
    if (t == 0) off[N_NODES] = N_EDGES;
}

// K1: compute + place messages. One 16-lane group per edge; block covers 16
// consecutive edges -> ea reads are a pure sequential stream (nt: read-once).
// x[src] is a random 512B read of an L3-resident 25.6 MB buffer (no longer
// thrashed by the ea stream). Message written fp32 to its CSR slot.
__global__ __launch_bounds__(256) void k_msg(
    const float* __restrict__ x,
    const int* __restrict__ ei,
    const float* __restrict__ ea,
    int* __restrict__ cursor,
    float* __restrict__ msg)
{
    const int lane = threadIdx.x & 63;
    const int c = lane & 15;
    const int grp = threadIdx.x >> 4;             // 0..15 in block
    const int e = blockIdx.x * 16 + grp;          // 37500*16 == 600000 exact

    int src = ei[e];                               // broadcast (same addr/16 lanes)
    int dst = ei[N_EDGES + e];
    int pos = 0;
    if (c == 0) pos = atomicAdd(&cursor[dst], 1);
    pos = __shfl(pos, lane & 48);

    const float* xr = x + (size_t)src * DIM + 8 * c;
    const float* er = ea + (size_t)e * DIM + 8 * c;
    f32x4 xv0 = *(const f32x4*)xr;
    f32x4 xv1 = *(const f32x4*)(xr + 4);
    f32x4 ev0 = __builtin_nontemporal_load((const f32x4*)er);
    f32x4 ev1 = __builtin_nontemporal_load((const f32x4*)(er + 4));
    f32x4 m0, m1;
#pragma unroll
    for (int j = 0; j < 4; j++) {
        m0[j] = fmaxf(xv0[j] + ev0[j], 0.f);
        m1[j] = fmaxf(xv1[j] + ev1[j], 0.f);
    }
    float* mr = msg + (size_t)pos * DIM + 8 * c;
    *(f32x4*)mr = m0;
    *(f32x4*)(mr + 4) = m1;
}

// K2: segment-sum of messages -> agg. One wave per node; the node's rows are
// CONTIGUOUS in msg, so all reads are sequential. 4 rows in flight per wave
// (group g handles rows g, g+4, ...), 2 KB per wave-iteration.
__global__ __launch_bounds__(256) void k_gather2(
    const float* __restrict__ msg,
    const int* __restrict__ off,
    float* __restrict__ agg)
{
    const int wave = threadIdx.x >> 6;
    const int lane = threadIdx.x & 63;
    const int g = lane >> 4;
    const int c = lane & 15;
    const int v = blockIdx.x * 4 + wave;
    if (v >= N_NODES) return;
    const int o0 = off[v], o1 = off[v + 1];
    const int deg = o1 - o0;
    f32x4 a0 = {0.f, 0.f, 0.f, 0.f};
    f32x4 a1 = {0.f, 0.f, 0.f, 0.f};
    const float* base = msg + (size_t)o0 * DIM + 8 * c;
    for (int r = g; r < deg; r += 4) {
        const float* mr = base + (size_t)r * DIM;
        f32x4 v0 = *(const f32x4*)mr;
        f32x4 v1 = *(const f32x4*)(mr + 4);
#pragma unroll
        for (int j = 0; j < 4; j++) { a0[j] += v0[j]; a1[j] += v1[j]; }
    }
#pragma unroll
    for (int j = 0; j < 4; j++) {
        a0[j] += __shfl_xor(a0[j], 16); a0[j] += __shfl_xor(a0[j], 32);
        a1[j] += __shfl_xor(a1[j], 16); a1[j] += __shfl_xor(a1[j], 32);
    }
    if (g == 0) {
        float* o = agg + (size_t)v * DIM + 8 * c;
        *(f32x4*)o = a0;
        *(f32x4*)(o + 4) = a1;
    }
}

// ---------------------------------------------------------------------------
// K3: fused  h0 = bf16(x+agg);  h1 = relu(h0@w1^T+b1);  h2 = h1@w2^T+b2 (fp32)
// + per-block column sum/sumsq of h2 (BN stats) into the block's OWN agg rows.
// ---------------------------------------------------------------------------
__global__ __launch_bounds__(256) void k_mlp(
    const float* __restrict__ x,
    const float* __restrict__ agg,
    const float* __restrict__ w1,
    const float* __restrict__ b1,
    const float* __restrict__ w2,
    const float* __restrict__ b2,
    float* __restrict__ h2out,
    float* __restrict__ pstat)   // == agg (non-const alias)
{
    __shared__ __align__(16) unsigned short lds[4][32][136];
    __shared__ float sm_s[4][DIM];
    __shared__ float sm_ss[4][DIM];
    const int wave = threadIdx.x >> 6;
    const int lane = threadIdx.x & 63;
    const int n = lane & 15;
    const int g = lane >> 4;
    const int r0 = blockIdx.x * 128 + wave * 32;

    s16x8 afrag[2][4];
#pragma unroll
    for (int tile = 0; tile < 2; tile++) {
        int row = r0 + tile * 16 + n;
        if (row > N_NODES - 1) row = N_NODES - 1;
        const float* xr = x + (size_t)row * DIM;
        const float* ar = agg + (size_t)row * DIM;
#pragma unroll
        for (int q = 0; q < 4; q++) {
            int k0 = 32 * q + 8 * g;
            f32x4 s0 = *(const f32x4*)(xr + k0);
            f32x4 s1 = *(const f32x4*)(xr + k0 + 4);
            f32x4 p0 = *(const f32x4*)(ar + k0);
            f32x4 p1 = *(const f32x4*)(ar + k0 + 4);
#pragma unroll
            for (int j = 0; j < 4; j++) { s0[j] += p0[j]; s1[j] += p1[j]; }
            afrag[tile][q] = cvt8(s0, s1);
        }
    }

#pragma unroll
    for (int t = 0; t < 8; t++) {
        f32x4 c0 = {0.f, 0.f, 0.f, 0.f};
        f32x4 c1 = {0.f, 0.f, 0.f, 0.f};
#pragma unroll
        for (int q = 0; q < 4; q++) {
            const float* wr = w1 + (16 * t + n) * DIM + 32 * q + 8 * g;
            s16x8 bfr = cvt8(*(const f32x4*)wr, *(const f32x4*)(wr + 4));
            c0 = __builtin_amdgcn_mfma_f32_16x16x32_bf16(afrag[0][q], bfr, c0, 0, 0, 0);
            c1 = __builtin_amdgcn_mfma_f32_16x16x32_bf16(afrag[1][q], bfr, c1, 0, 0, 0);
        }
        float bias = b1[16 * t + n];
#pragma unroll
        for (int rr = 0; rr < 4; rr++) {
            lds[wave][4 * g + rr][16 * t + n]      = f2b(fmaxf(c0[rr] + bias, 0.f));
            lds[wave][16 + 4 * g + rr][16 * t + n] = f2b(fmaxf(c1[rr] + bias, 0.f));
        }
    }

    s16x8 a2[2][4];
#pragma unroll
    for (int tile = 0; tile < 2; tile++) {
#pragma unroll
        for (int q = 0; q < 4; q++) {
            union { u16x8 u; s16x8 s; } tmp;
            tmp.u = *(const u16x8*)&lds[wave][tile * 16 + n][32 * q + 8 * g];
            a2[tile][q] = tmp.s;
        }
    }

#pragma unroll
    for (int t = 0; t < 8; t++) {
        f32x4 c0 = {0.f, 0.f, 0.f, 0.f};
        f32x4 c1 = {0.f, 0.f, 0.f, 0.f};
#pragma unroll
        for (int q = 0; q < 4; q++) {
            const float* wr = w2 + (16 * t + n) * DIM + 32 * q + 8 * g;
            s16x8 bfr = cvt8(*(const f32x4*)wr, *(const f32x4*)(wr + 4));
            c0 = __builtin_amdgcn_mfma_f32_16x16x32_bf16(a2[0][q], bfr, c0, 0, 0, 0);
            c1 = __builtin_amdgcn_mfma_f32_16x16x32_bf16(a2[1][q], bfr, c1, 0, 0, 0);
        }
        float bias = b2[16 * t + n];
        float cs = 0.f, css = 0.f;
#pragma unroll
        for (int rr = 0; rr < 4; rr++) {
            int row0 = r0 + 4 * g + rr;
            int row1 = r0 + 16 + 4 * g + rr;
            float v0 = c0[rr] + bias;
            float v1 = c1[rr] + bias;
            if (row0 < N_NODES) {
                h2out[(size_t)row0 * DIM + 16 * t + n] = v0;
                cs += v0; css += v0 * v0;
            }
            if (row1 < N_NODES) {
                h2out[(size_t)row1 * DIM + 16 * t + n] = v1;
                cs += v1; css += v1 * v1;
            }
        }
        cs  += __shfl_xor(cs, 16);  cs  += __shfl_xor(cs, 32);
        css += __shfl_xor(css, 16); css += __shfl_xor(css, 32);
        if (lane < 16) { sm_s[wave][16 * t + lane] = cs; sm_ss[wave][16 * t + lane] = css; }
    }

    __syncthreads();
    const int tid = threadIdx.x;
    if (tid < DIM) {
        float S  = sm_s[0][tid] + sm_s[1][tid] + sm_s[2][tid] + sm_s[3][tid];
        float SS = sm_ss[0][tid] + sm_ss[1][tid] + sm_ss[2][tid] + sm_ss[3][tid];
        float* ps = pstat + (size_t)blockIdx.x * 128 * DIM;
        ps[tid]       = S;
        ps[DIM + tid] = SS;
    }
}

// ---------------------------------------------------------------------------
// K4: BN finalize -- reduce 391 per-block partials, write scale/shift
// ---------------------------------------------------------------------------
__global__ __launch_bounds__(512) void k_bn_finalize(
    const float* __restrict__ pstat,
    const float* __restrict__ bnw, const float* __restrict__ bnb,
    float* __restrict__ scale, float* __restrict__ shiftv)
{
    __shared__ float as[4][DIM], ass[4][DIM];
    const int t = threadIdx.x;
    const int c = t & 127, q = t >> 7;
    float s = 0.f, ss = 0.f;
    for (int b = q; b < NBLK_MLP; b += 4) {
        const float* ps = pstat + (size_t)b * 128 * DIM;
        s += ps[c]; ss += ps[DIM + c];
    }
    as[q][c] = s; ass[q][c] = ss;
    __syncthreads();
    if (t < DIM) {
        float S  = as[0][t] + as[1][t] + as[2][t] + as[3][t];
        float SS = ass[0][t] + ass[1][t] + ass[2][t] + ass[3][t];
        const float invN = 1.0f / (float)N_NODES;
        float mean = S * invN;
        float var = fmaxf(SS * invN - mean * mean, 0.0f);
        float sc = bnw[t] * rsqrtf(var + 1e-5f);
        scale[t] = sc;
        shiftv[t] = bnb[t] - mean * sc;
    }
}

// ---------------------------------------------------------------------------
// K5: out = relu(h2*scale + shift), fp32 in place on d_out
// ---------------------------------------------------------------------------
__global__ __launch_bounds__(256) void k_bn_apply(
    float* __restrict__ h2,
    const float* __restrict__ scale, const float* __restrict__ shiftv)
{
    int t = blockIdx.x * 256 + threadIdx.x;
    int col0 = (t * 8) & (DIM - 1);
    float* p = h2 + (size_t)t * 8;
    f32x4 h0 = *(const f32x4*)p;
    f32x4 h1 = *(const f32x4*)(p + 4);
    f32x4 s0 = *(const f32x4*)(scale + col0);
    f32x4 s1 = *(const f32x4*)(scale + col0 + 4);
    f32x4 f0 = *(const f32x4*)(shiftv + col0);
    f32x4 f1 = *(const f32x4*)(shiftv + col0 + 4);
    f32x4 o0, o1;
#pragma unroll
    for (int j = 0; j < 4; j++) {
        o0[j] = fmaxf(fmaf(h0[j], s0[j], f0[j]), 0.0f);
        o1[j] = fmaxf(fmaf(h1[j], s1[j], f1[j]), 0.0f);
    }
    *(f32x4*)p = o0;
    *(f32x4*)(p + 4) = o1;
}

// ---------------------------------------------------------------------------
extern "C" void kernel_launch(void* const* d_in, const int* in_sizes, int n_in,
                              void* d_out, int out_size, void* d_ws, size_t ws_size,
                              hipStream_t stream) {
    const float* x   = (const float*)d_in[0];
    const int*   ei  = (const int*)d_in[1];
    const float* ea  = (const float*)d_in[2];
    const float* w1  = (const float*)d_in[3];
    const float* b1  = (const float*)d_in[4];
    const float* w2  = (const float*)d_in[5];
    const float* b2  = (const float*)d_in[6];
    const float* bnw = (const float*)d_in[7];
    const float* bnb = (const float*)d_in[8];

    char* ws = (char*)d_ws;
    float* agg     = (float*)ws;
    float* scale   = (float*)(ws + 102400);          // agg row 200 (dead)
    float* shiftv  = (float*)(ws + 102912);          // agg row 201 (dead)
    float* msg     = (float*)(ws + (size_t)(32 << 20)); // 293 MB @ +32 MiB
    float* h2      = (float*)d_out;

    char* ob = (char*)d_out;
    int*  off    = (int*)ob;
    int*  cursor = (int*)(ob + 200064);   // doubles as count[] during k_hist

    // zero only the count/cursor region
    hipMemsetAsync(ob + 200064, 0, 200000, stream);

    k_hist<<<(N_EDGES + 255) / 256, 256, 0, stream>>>(ei, cursor);
    k_scan<<<1, 1024, 0, stream>>>(off, cursor);
    k_msg<<<N_EDGES / 16, 256, 0, stream>>>(x, ei, ea, cursor, msg);
    k_gather2<<<(N_NODES + 3) / 4, 256, 0, stream>>>(msg, off, agg);
    k_mlp<<<NBLK_MLP, 256, 0, stream>>>(x, agg, w1, b1, w2, b2, h2, agg);
    k_bn_finalize<<<1, 512, 0, stream>>>(agg, bnw, bnb, scale, shiftv);
    k_bn_apply<<<N_NODES * DIM / 8 / 256, 256, 0, stream>>>(h2, scale, shiftv);
}

// Round 4
// 719.635 us; speedup vs baseline: 1.0865x; 1.0865x over previous
//
#include <hip/hip_runtime.h>
#include <hip/hip_cooperative_groups.h>

namespace cg = cooperative_groups;

#define N_NODES 50000
#define N_EDGES 600000
#define DIM 128
#define NBLK_MLP ((N_NODES + 127) / 128)   // 391

typedef __attribute__((ext_vector_type(8))) short s16x8;
typedef __attribute__((ext_vector_type(8))) unsigned short u16x8;
typedef __attribute__((ext_vector_type(4))) float f32x4;
typedef __attribute__((ext_vector_type(2))) float f32x2;

__device__ __forceinline__ unsigned short f2b(float f) {
    union { float f; unsigned int i; } v;
    v.f = f;
    unsigned int i = v.i;
    return (unsigned short)((i + 0x7FFFu + ((i >> 16) & 1u)) >> 16);
}

// pack 8 fp32 -> 8 bf16 (RNE)
__device__ __forceinline__ s16x8 cvt8(f32x4 a, f32x4 b) {
    union { u16x8 u; s16x8 s; } t;
#pragma unroll
    for (int j = 0; j < 4; j++) { t.u[j] = f2b(a[j]); t.u[4 + j] = f2b(b[j]); }
    return t.s;
}

// ---------------------------------------------------------------------------
// Phase A: CSR by destination. R1 random-read gather is kept verbatim (R1
// ILP-null + R2 sequentialization-regression proved it near the memory
// system's limit for this pattern). Changes vs R1: edge rank recorded in
// k_hist so the placement pass needs NO atomics (halves memory-side RMWs).
//
// d_out scratch (dead until tail writes final output):
//   off     int[50001]   @ byte 0
//   count   int[50000]   @ byte 200,064
//   pairs   int2[600000] @ byte 400,128
// ws: agg fp32[50000][128] @ 0 ; rank int[600000] @ 32 MiB ;
//     pstat fp32[391*256] @ 36 MiB ; scale/shift (fallback) @ 37 MiB
// ---------------------------------------------------------------------------

// K0a: histogram of destinations + per-edge rank within destination
__global__ __launch_bounds__(256) void k_histrank(
    const int* __restrict__ ei, int* __restrict__ count,
    int* __restrict__ rank)
{
    int t = blockIdx.x * 256 + threadIdx.x;
    if (t < N_EDGES) rank[t] = atomicAdd(&count[ei[N_EDGES + t]], 1);
}

// K0b: exclusive scan of counts -> off[0..N]
__global__ __launch_bounds__(1024) void k_scan(
    int* __restrict__ off, const int* __restrict__ cnt)
{
    __shared__ int part[1024];
    const int CH = (N_NODES + 1023) / 1024;  // 49
    const int t = threadIdx.x;
    const int lo = t * CH;
    const int hi = (lo + CH < N_NODES) ? lo + CH : N_NODES;
    int s = 0;
    for (int v = lo; v < hi; v++) s += cnt[v];
    part[t] = s;
    __syncthreads();
    for (int d = 1; d < 1024; d <<= 1) {
        int val = (t >= d) ? part[t - d] : 0;
        __syncthreads();
        part[t] += val;
        __syncthreads();
    }
    int run = (t == 0) ? 0 : part[t - 1];
    for (int v = lo; v < hi; v++) {
        off[v] = run;
        run += cnt[v];
    }
    if (t == 0) off[N_NODES] = N_EDGES;
}

// K0c: atomic-free placement of packed {eid, src} into CSR slots
__global__ __launch_bounds__(256) void k_place(
    const int* __restrict__ ei, const int* __restrict__ off,
    const int* __restrict__ rank, int2* __restrict__ pairs)
{
    int t = blockIdx.x * 256 + threadIdx.x;
    if (t < N_EDGES) {
        int dst = ei[N_EDGES + t];
        int pos = off[dst] + rank[t];
        int2 p; p.x = t; p.y = ei[t];
        pairs[pos] = p;
    }
}

// K1: gather-reduce (R1 version, unchanged: proven fastest).
__global__ __launch_bounds__(256) void k_gather(
    const float* __restrict__ x,
    const float* __restrict__ ea,
    const int* __restrict__ off,
    const int2* __restrict__ pairs,
    float* __restrict__ agg)
{
    const int wave = threadIdx.x >> 6;
    const int lane = threadIdx.x & 63;
    const int g = lane >> 4;        // edge sub-group 0..3
    const int c = lane & 15;        // dims 8c .. 8c+7
    const int v = blockIdx.x * 4 + wave;
    if (v >= N_NODES) return;
    const int o0 = off[v], o1 = off[v + 1];
    f32x4 a0 = {0.f, 0.f, 0.f, 0.f};
    f32x4 a1 = {0.f, 0.f, 0.f, 0.f};
    for (int e = o0 + g; e < o1; e += 4) {
        int2 p = pairs[e];          // same addr across 16 lanes: HW broadcast
        const float* xr = x + (size_t)p.y * DIM + 8 * c;
        const float* er = ea + (size_t)p.x * DIM + 8 * c;
        f32x4 xv0 = *(const f32x4*)xr;
        f32x4 xv1 = *(const f32x4*)(xr + 4);
        f32x4 ev0 = __builtin_nontemporal_load((const f32x4*)er);
        f32x4 ev1 = __builtin_nontemporal_load((const f32x4*)(er + 4));
#pragma unroll
        for (int j = 0; j < 4; j++) {
            a0[j] += fmaxf(xv0[j] + ev0[j], 0.f);
            a1[j] += fmaxf(xv1[j] + ev1[j], 0.f);
        }
    }
#pragma unroll
    for (int j = 0; j < 4; j++) {
        a0[j] += __shfl_xor(a0[j], 16); a0[j] += __shfl_xor(a0[j], 32);
        a1[j] += __shfl_xor(a1[j], 16); a1[j] += __shfl_xor(a1[j], 32);
    }
    if (g == 0) {
        float* o = agg + (size_t)v * DIM + 8 * c;
        *(f32x4*)o = a0;
        *(f32x4*)(o + 4) = a1;
    }
}

// ---------------------------------------------------------------------------
// K2 (cooperative): h0=bf16(x+agg); h1=relu(h0@w1^T+b1); h2=h1@w2^T+b2 kept
// in 64 regs/thread; BN stats -> pstat; grid.sync(); per-block finalize;
// out = relu(h2*scale+shift) written ONCE. Saves the 51 MB h2 round-trip.
// ---------------------------------------------------------------------------
__global__ __launch_bounds__(256, 2) void k_tail(
    const float* __restrict__ x,
    const float* __restrict__ agg,
    const float* __restrict__ w1,
    const float* __restrict__ b1,
    const float* __restrict__ w2,
    const float* __restrict__ b2,
    const float* __restrict__ bnw,
    const float* __restrict__ bnb,
    float* __restrict__ pstat,
    float* __restrict__ out)
{
    __shared__ __align__(16) unsigned short lds[4][32][136];
    __shared__ float sm_s[4][DIM];
    __shared__ float sm_ss[4][DIM];
    __shared__ float sm_scale[DIM];
    __shared__ float sm_shift[DIM];
    const int wave = threadIdx.x >> 6;
    const int lane = threadIdx.x & 63;
    const int n = lane & 15;
    const int g = lane >> 4;
    const int r0 = blockIdx.x * 128 + wave * 32;

    s16x8 afrag[2][4];
#pragma unroll
    for (int tile = 0; tile < 2; tile++) {
        int row = r0 + tile * 16 + n;
        if (row > N_NODES - 1) row = N_NODES - 1;
        const float* xr = x + (size_t)row * DIM;
        const float* ar = agg + (size_t)row * DIM;
#pragma unroll
        for (int q = 0; q < 4; q++) {
            int k0 = 32 * q + 8 * g;
            f32x4 s0 = *(const f32x4*)(xr + k0);
            f32x4 s1 = *(const f32x4*)(xr + k0 + 4);
            f32x4 p0 = *(const f32x4*)(ar + k0);
            f32x4 p1 = *(const f32x4*)(ar + k0 + 4);
#pragma unroll
            for (int j = 0; j < 4; j++) { s0[j] += p0[j]; s1[j] += p1[j]; }
            afrag[tile][q] = cvt8(s0, s1);
        }
    }

#pragma unroll
    for (int t = 0; t < 8; t++) {
        f32x4 c0 = {0.f, 0.f, 0.f, 0.f};
        f32x4 c1 = {0.f, 0.f, 0.f, 0.f};
#pragma unroll
        for (int q = 0; q < 4; q++) {
            const float* wr = w1 + (16 * t + n) * DIM + 32 * q + 8 * g;
            s16x8 bfr = cvt8(*(const f32x4*)wr, *(const f32x4*)(wr + 4));
            c0 = __builtin_amdgcn_mfma_f32_16x16x32_bf16(afrag[0][q], bfr, c0, 0, 0, 0);
            c1 = __builtin_amdgcn_mfma_f32_16x16x32_bf16(afrag[1][q], bfr, c1, 0, 0, 0);
        }
        float bias = b1[16 * t + n];
#pragma unroll
        for (int rr = 0; rr < 4; rr++) {
            lds[wave][4 * g + rr][16 * t + n]      = f2b(fmaxf(c0[rr] + bias, 0.f));
            lds[wave][16 + 4 * g + rr][16 * t + n] = f2b(fmaxf(c1[rr] + bias, 0.f));
        }
    }

    s16x8 a2[2][4];
#pragma unroll
    for (int tile = 0; tile < 2; tile++) {
#pragma unroll
        for (int q = 0; q < 4; q++) {
            union { u16x8 u; s16x8 s; } tmp;
            tmp.u = *(const u16x8*)&lds[wave][tile * 16 + n][32 * q + 8 * g];
            a2[tile][q] = tmp.s;
        }
    }

    float h2r[8][8];   // [t][rr: 0-3 = tile0 rows, 4-7 = tile1 rows]
#pragma unroll
    for (int t = 0; t < 8; t++) {
        f32x4 c0 = {0.f, 0.f, 0.f, 0.f};
        f32x4 c1 = {0.f, 0.f, 0.f, 0.f};
#pragma unroll
        for (int q = 0; q < 4; q++) {
            const float* wr = w2 + (16 * t + n) * DIM + 32 * q + 8 * g;
            s16x8 bfr = cvt8(*(const f32x4*)wr, *(const f32x4*)(wr + 4));
            c0 = __builtin_amdgcn_mfma_f32_16x16x32_bf16(a2[0][q], bfr, c0, 0, 0, 0);
            c1 = __builtin_amdgcn_mfma_f32_16x16x32_bf16(a2[1][q], bfr, c1, 0, 0, 0);
        }
        float bias = b2[16 * t + n];
        float cs = 0.f, css = 0.f;
#pragma unroll
        for (int rr = 0; rr < 4; rr++) {
            int row0 = r0 + 4 * g + rr;
            int row1 = r0 + 16 + 4 * g + rr;
            float v0 = c0[rr] + bias;
            float v1 = c1[rr] + bias;
            h2r[t][rr]     = v0;
            h2r[t][4 + rr] = v1;
            if (row0 < N_NODES) { cs += v0; css += v0 * v0; }
            if (row1 < N_NODES) { cs += v1; css += v1 * v1; }
        }
        cs  += __shfl_xor(cs, 16);  cs  += __shfl_xor(cs, 32);
        css += __shfl_xor(css, 16); css += __shfl_xor(css, 32);
        if (lane < 16) { sm_s[wave][16 * t + lane] = cs; sm_ss[wave][16 * t + lane] = css; }
    }

    __syncthreads();
    const int tid = threadIdx.x;
    if (tid < DIM) {
        float S  = sm_s[0][tid] + sm_s[1][tid] + sm_s[2][tid] + sm_s[3][tid];
        float SS = sm_ss[0][tid] + sm_ss[1][tid] + sm_ss[2][tid] + sm_ss[3][tid];
        pstat[blockIdx.x * 256 + tid]       = S;
        pstat[blockIdx.x * 256 + DIM + tid] = SS;
    }
    __threadfence();
    cg::this_grid().sync();

    // per-block finalize (391 x 1 KB, L2-resident)
    if (tid < DIM) {
        float S = 0.f, SS = 0.f;
        for (int b = 0; b < NBLK_MLP; b++) {
            S  += pstat[b * 256 + tid];
            SS += pstat[b * 256 + DIM + tid];
        }
        const float invN = 1.0f / (float)N_NODES;
        float mean = S * invN;
        float var = fmaxf(SS * invN - mean * mean, 0.0f);
        float sc = bnw[tid] * rsqrtf(var + 1e-5f);
        sm_scale[tid] = sc;
        sm_shift[tid] = bnb[tid] - mean * sc;
    }
    __syncthreads();

#pragma unroll
    for (int t = 0; t < 8; t++) {
        float sc = sm_scale[16 * t + n];
        float sh = sm_shift[16 * t + n];
#pragma unroll
        for (int rr = 0; rr < 4; rr++) {
            int row0 = r0 + 4 * g + rr;
            int row1 = r0 + 16 + 4 * g + rr;
            if (row0 < N_NODES)
                out[(size_t)row0 * DIM + 16 * t + n] = fmaxf(fmaf(h2r[t][rr], sc, sh), 0.f);
            if (row1 < N_NODES)
                out[(size_t)row1 * DIM + 16 * t + n] = fmaxf(fmaf(h2r[t][4 + rr], sc, sh), 0.f);
        }
    }
}

// ---------------------------------------------------------------------------
// Fallback split tail (used only if cooperative launch is refused)
// ---------------------------------------------------------------------------
__global__ __launch_bounds__(256) void k_mlp(
    const float* __restrict__ x, const float* __restrict__ agg,
    const float* __restrict__ w1, const float* __restrict__ b1,
    const float* __restrict__ w2, const float* __restrict__ b2,
    float* __restrict__ h2out, float* __restrict__ pstat)
{
    __shared__ __align__(16) unsigned short lds[4][32][136];
    __shared__ float sm_s[4][DIM];
    __shared__ float sm_ss[4][DIM];
    const int wave = threadIdx.x >> 6;
    const int lane = threadIdx.x & 63;
    const int n = lane & 15;
    const int g = lane >> 4;
    const int r0 = blockIdx.x * 128 + wave * 32;

    s16x8 afrag[2][4];
#pragma unroll
    for (int tile = 0; tile < 2; tile++) {
        int row = r0 + tile * 16 + n;
        if (row > N_NODES - 1) row = N_NODES - 1;
        const float* xr = x + (size_t)row * DIM;
        const float* ar = agg + (size_t)row * DIM;
#pragma unroll
        for (int q = 0; q < 4; q++) {
            int k0 = 32 * q + 8 * g;
            f32x4 s0 = *(const f32x4*)(xr + k0);
            f32x4 s1 = *(const f32x4*)(xr + k0 + 4);
            f32x4 p0 = *(const f32x4*)(ar + k0);
            f32x4 p1 = *(const f32x4*)(ar + k0 + 4);
#pragma unroll
            for (int j = 0; j < 4; j++) { s0[j] += p0[j]; s1[j] += p1[j]; }
            afrag[tile][q] = cvt8(s0, s1);
        }
    }
#pragma unroll
    for (int t = 0; t < 8; t++) {
        f32x4 c0 = {0.f, 0.f, 0.f, 0.f};
        f32x4 c1 = {0.f, 0.f, 0.f, 0.f};
#pragma unroll
        for (int q = 0; q < 4; q++) {
            const float* wr = w1 + (16 * t + n) * DIM + 32 * q + 8 * g;
            s16x8 bfr = cvt8(*(const f32x4*)wr, *(const f32x4*)(wr + 4));
            c0 = __builtin_amdgcn_mfma_f32_16x16x32_bf16(afrag[0][q], bfr, c0, 0, 0, 0);
            c1 = __builtin_amdgcn_mfma_f32_16x16x32_bf16(afrag[1][q], bfr, c1, 0, 0, 0);
        }
        float bias = b1[16 * t + n];
#pragma unroll
        for (int rr = 0; rr < 4; rr++) {
            lds[wave][4 * g + rr][16 * t + n]      = f2b(fmaxf(c0[rr] + bias, 0.f));
            lds[wave][16 + 4 * g + rr][16 * t + n] = f2b(fmaxf(c1[rr] + bias, 0.f));
        }
    }
    s16x8 a2[2][4];
#pragma unroll
    for (int tile = 0; tile < 2; tile++) {
#pragma unroll
        for (int q = 0; q < 4; q++) {
            union { u16x8 u; s16x8 s; } tmp;
            tmp.u = *(const u16x8*)&lds[wave][tile * 16 + n][32 * q + 8 * g];
            a2[tile][q] = tmp.s;
        }
    }
#pragma unroll
    for (int t = 0; t < 8; t++) {
        f32x4 c0 = {0.f, 0.f, 0.f, 0.f};
        f32x4 c1 = {0.f, 0.f, 0.f, 0.f};
#pragma unroll
        for (int q = 0; q < 4; q++) {
            const float* wr = w2 + (16 * t + n) * DIM + 32 * q + 8 * g;
            s16x8 bfr = cvt8(*(const f32x4*)wr, *(const f32x4*)(wr + 4));
            c0 = __builtin_amdgcn_mfma_f32_16x16x32_bf16(a2[0][q], bfr, c0, 0, 0, 0);
            c1 = __builtin_amdgcn_mfma_f32_16x16x32_bf16(a2[1][q], bfr, c1, 0, 0, 0);
        }
        float bias = b2[16 * t + n];
        float cs = 0.f, css = 0.f;
#pragma unroll
        for (int rr = 0; rr < 4; rr++) {
            int row0 = r0 + 4 * g + rr;
            int row1 = r0 + 16 + 4 * g + rr;
            float v0 = c0[rr] + bias;
            float v1 = c1[rr] + bias;
            if (row0 < N_NODES) { h2out[(size_t)row0 * DIM + 16 * t + n] = v0; cs += v0; css += v0 * v0; }
            if (row1 < N_NODES) { h2out[(size_t)row1 * DIM + 16 * t + n] = v1; cs += v1; css += v1 * v1; }
        }
        cs  += __shfl_xor(cs, 16);  cs  += __shfl_xor(cs, 32);
        css += __shfl_xor(css, 16); css += __shfl_xor(css, 32);
        if (lane < 16) { sm_s[wave][16 * t + lane] = cs; sm_ss[wave][16 * t + lane] = css; }
    }
    __syncthreads();
    const int tid = threadIdx.x;
    if (tid < DIM) {
        float S  = sm_s[0][tid] + sm_s[1][tid] + sm_s[2][tid] + sm_s[3][tid];
        float SS = sm_ss[0][tid] + sm_ss[1][tid] + sm_ss[2][tid] + sm_ss[3][tid];
        pstat[blockIdx.x * 256 + tid]       = S;
        pstat[blockIdx.x * 256 + DIM + tid] = SS;
    }
}

__global__ __launch_bounds__(512) void k_bn_finalize(
    const float* __restrict__ pstat,
    const float* __restrict__ bnw, const float* __restrict__ bnb,
    float* __restrict__ scale, float* __restrict__ shiftv)
{
    __shared__ float as[4][DIM], ass[4][DIM];
    const int t = threadIdx.x;
    const int c = t & 127, q = t >> 7;
    float s = 0.f, ss = 0.f;
    for (int b = q; b < NBLK_MLP; b += 4) {
        s  += pstat[b * 256 + c];
        ss += pstat[b * 256 + DIM + c];
    }
    as[q][c] = s; ass[q][c] = ss;
    __syncthreads();
    if (t < DIM) {
        float S  = as[0][t] + as[1][t] + as[2][t] + as[3][t];
        float SS = ass[0][t] + ass[1][t] + ass[2][t] + ass[3][t];
        const float invN = 1.0f / (float)N_NODES;
        float mean = S * invN;
        float var = fmaxf(SS * invN - mean * mean, 0.0f);
        float sc = bnw[t] * rsqrtf(var + 1e-5f);
        scale[t] = sc;
        shiftv[t] = bnb[t] - mean * sc;
    }
}

__global__ __launch_bounds__(256) void k_bn_apply(
    float* __restrict__ h2,
    const float* __restrict__ scale, const float* __restrict__ shiftv)
{
    int t = blockIdx.x * 256 + threadIdx.x;
    int col0 = (t * 8) & (DIM - 1);
    float* p = h2 + (size_t)t * 8;
    f32x4 h0 = *(const f32x4*)p;
    f32x4 h1 = *(const f32x4*)(p + 4);
    f32x4 s0 = *(const f32x4*)(scale + col0);
    f32x4 s1 = *(const f32x4*)(scale + col0 + 4);
    f32x4 f0 = *(const f32x4*)(shiftv + col0);
    f32x4 f1 = *(const f32x4*)(shiftv + col0 + 4);
    f32x4 o0, o1;
#pragma unroll
    for (int j = 0; j < 4; j++) {
        o0[j] = fmaxf(fmaf(h0[j], s0[j], f0[j]), 0.0f);
        o1[j] = fmaxf(fmaf(h1[j], s1[j], f1[j]), 0.0f);
    }
    *(f32x4*)p = o0;
    *(f32x4*)(p + 4) = o1;
}

// ---------------------------------------------------------------------------
extern "C" void kernel_launch(void* const* d_in, const int* in_sizes, int n_in,
                              void* d_out, int out_size, void* d_ws, size_t ws_size,
                              hipStream_t stream) {
    const float* x   = (const float*)d_in[0];
    const int*   ei  = (const int*)d_in[1];
    const float* ea  = (const float*)d_in[2];
    const float* w1  = (const float*)d_in[3];
    const float* b1  = (const float*)d_in[4];
    const float* w2  = (const float*)d_in[5];
    const float* b2  = (const float*)d_in[6];
    const float* bnw = (const float*)d_in[7];
    const float* bnb = (const float*)d_in[8];

    char* ws = (char*)d_ws;
    float* agg    = (float*)ws;                            // 25.6 MB
    int*   rank   = (int*)(ws + (size_t)(32 << 20));       // 2.4 MB
    float* pstat  = (float*)(ws + (size_t)(36 << 20));     // 400 KB
    float* scale  = (float*)(ws + (size_t)(37 << 20));     // fallback only
    float* shiftv = (float*)(ws + (size_t)(37 << 20) + 512);
    float* outp   = (float*)d_out;

    char* ob = (char*)d_out;
    int*  off   = (int*)ob;
    int*  count = (int*)(ob + 200064);
    int2* pairs = (int2*)(ob + 400128);

    // zero the count region only
    hipMemsetAsync(ob + 200064, 0, 200000, stream);

    k_histrank<<<(N_EDGES + 255) / 256, 256, 0, stream>>>(ei, count, rank);
    k_scan<<<1, 1024, 0, stream>>>(off, count);
    k_place<<<(N_EDGES + 255) / 256, 256, 0, stream>>>(ei, off, rank, pairs);
    k_gather<<<(N_NODES + 3) / 4, 256, 0, stream>>>(x, ea, off, pairs, agg);

    {
        const float* ax = x;  const float* aa = agg;
        const float* a1p = w1; const float* a2p = b1;
        const float* a3p = w2; const float* a4p = b2;
        const float* a5p = bnw; const float* a6p = bnb;
        float* a7p = pstat; float* a8p = outp;
        void* args[] = { (void*)&ax, (void*)&aa, (void*)&a1p, (void*)&a2p,
                         (void*)&a3p, (void*)&a4p, (void*)&a5p, (void*)&a6p,
                         (void*)&a7p, (void*)&a8p };
        hipError_t ce = hipLaunchCooperativeKernel(
            (const void*)k_tail, dim3(NBLK_MLP), dim3(256), args, 0, stream);
        if (ce != hipSuccess) {
            (void)hipGetLastError();  // clear sticky error, use split path
            k_mlp<<<NBLK_MLP, 256, 0, stream>>>(x, agg, w1, b1, w2, b2, outp, pstat);
            k_bn_finalize<<<1, 512, 0, stream>>>(pstat, bnw, bnb, scale, shiftv);
            k_bn_apply<<<N_NODES * DIM / 8 / 256, 256, 0, stream>>>(outp, scale, shiftv);
        }
    }
}